// Round 1
// baseline (434.384 us; speedup 1.0000x reference)
//
#include <hip/hip_runtime.h>

#define NSEG 16
#define OUT_COLS 384                 // 256 coarse + 128 fine, row stride of out
#define OUT_ELEMS (NSEG * OUT_COLS)  // 6144

// Fused ragged segment-mean. Grid is split: blocks [0, fineBlocks) stream
// feats_f (D=128), the rest stream feats_c (D=256). Each thread holds a fixed
// 4-float column slice (float4) and walks rows; segment id is tracked
// incrementally against the length cumsum. Partial sums are pre-scaled by
// 1/len and atomically flushed into a per-(blockIdx%nRep) replica to avoid
// same-address atomic serialization.
__global__ __launch_bounds__(256) void seg_mean_kernel(
    const float4* __restrict__ ff, const float4* __restrict__ fc,
    const int* __restrict__ len_f, const int* __restrict__ len_c,
    float* __restrict__ outbuf, int fineBlocks, int iterF, int iterC, int nRep)
{
    __shared__ int   s_cum[NSEG];
    __shared__ float s_inv[NSEG];
    const bool fine = (int)blockIdx.x < fineBlocks;
    const int* len = fine ? len_f : len_c;
    if (threadIdx.x == 0) {
        int c = 0;
        for (int i = 0; i < NSEG; ++i) {
            int l = len[i];
            c += l;
            s_cum[i] = c;
            s_inv[i] = 1.0f / (float)l;
        }
    }
    __syncthreads();

    const int t = threadIdx.x;
    float* rep = outbuf + ((int)blockIdx.x % nRep) * OUT_ELEMS;

    int base, iters, colMask, rowShift, outOff;
    const float4* src;
    if (fine) {
        base = (int)blockIdx.x * 256 * iterF;  // float4 index
        iters = iterF; colMask = 31; rowShift = 5; outOff = 256; src = ff;
    } else {
        base = ((int)blockIdx.x - fineBlocks) * 256 * iterC;
        iters = iterC; colMask = 63; rowShift = 6; outOff = 0; src = fc;
    }
    // base is a multiple of 256 and (colMask+1) | 256, so the float4-column of
    // each thread is invariant across iterations.
    const int col = (t & colMask) << 2;  // float column within D
    const int idx0 = base + t;

    int seg = 0;
    {
        int row = idx0 >> rowShift;
        while (row >= s_cum[seg]) ++seg;
    }
    int curEnd = s_cum[seg];
    float4 acc = make_float4(0.f, 0.f, 0.f, 0.f);

    for (int i = 0; i < iters; ++i) {
        const int idx = idx0 + (i << 8);   // +i*256
        const int r = idx >> rowShift;
        if (r >= curEnd) {                 // crossed a segment boundary: flush
            const float inv = s_inv[seg];
            float* o = rep + seg * OUT_COLS + outOff + col;
            atomicAdd(o + 0, acc.x * inv);
            atomicAdd(o + 1, acc.y * inv);
            atomicAdd(o + 2, acc.z * inv);
            atomicAdd(o + 3, acc.w * inv);
            acc = make_float4(0.f, 0.f, 0.f, 0.f);
            while (r >= s_cum[seg]) ++seg;
            curEnd = s_cum[seg];
        }
        const float4 v = src[idx];
        acc.x += v.x; acc.y += v.y; acc.z += v.z; acc.w += v.w;
    }
    {   // final flush
        const float inv = s_inv[seg];
        float* o = rep + seg * OUT_COLS + outOff + col;
        atomicAdd(o + 0, acc.x * inv);
        atomicAdd(o + 1, acc.y * inv);
        atomicAdd(o + 2, acc.z * inv);
        atomicAdd(o + 3, acc.w * inv);
    }
}

// Sum the nRep replicas into d_out (also provides the zero-init of d_out,
// which the harness re-poisons to 0xAA before every timed launch).
__global__ __launch_bounds__(256) void reduce_replicas_kernel(
    const float* __restrict__ ws, float* __restrict__ out, int nRep)
{
    const int j = blockIdx.x * blockDim.x + threadIdx.x;
    if (j < OUT_ELEMS) {
        float s = 0.f;
        for (int r = 0; r < nRep; ++r) s += ws[r * OUT_ELEMS + j];
        out[j] = s;
    }
}

extern "C" void kernel_launch(void* const* d_in, const int* in_sizes, int n_in,
                              void* d_out, int out_size, void* d_ws, size_t ws_size,
                              hipStream_t stream) {
    const float4* ff = (const float4*)d_in[0];   // feats_f [524288,128] f32
    const float4* fc = (const float4*)d_in[1];   // feats_c [32768,256]  f32
    const int* lf = (const int*)d_in[2];         // lengths_f [16] i32
    const int* lc = (const int*)d_in[3];         // lengths_c [16] i32
    float* out = (float*)d_out;                  // [16,384] f32

    const int NF4 = in_sizes[0] / 4;             // 16,777,216 float4
    const int NC4 = in_sizes[1] / 4;             //  2,097,152 float4
    const int iterF = 32, iterC = 16;
    const int fineBlocks   = NF4 / (256 * iterF);   // 2048
    const int coarseBlocks = NC4 / (256 * iterC);   // 512

    int nRep = (int)(ws_size / (OUT_ELEMS * sizeof(float)));
    if (nRep > 32) nRep = 32;
    if (nRep < 1)  nRep = 1;  // degenerate ws: single accumulator in ws[0]

    const size_t repBytes = (size_t)nRep * OUT_ELEMS * sizeof(float);
    hipMemsetAsync(d_ws, 0, repBytes, stream);

    seg_mean_kernel<<<fineBlocks + coarseBlocks, 256, 0, stream>>>(
        ff, fc, lf, lc, (float*)d_ws, fineBlocks, iterF, iterC, nRep);

    reduce_replicas_kernel<<<(OUT_ELEMS + 255) / 256, 256, 0, stream>>>(
        (const float*)d_ws, out, nRep);
}

// Round 2
// 411.996 us; speedup vs baseline: 1.0543x; 1.0543x over previous
//
#include <hip/hip_runtime.h>

#define NSEG 16
#define OUT_COLS 384                 // 256 coarse + 128 fine, row stride of out
#define OUT_ELEMS (NSEG * OUT_COLS)  // 6144

// Fused ragged segment-mean. Grid is split: blocks [0, fineBlocks) stream
// feats_f (D=128), the rest stream feats_c (D=256). Each thread holds a fixed
// 4-float column slice (float4) and walks rows. The segment-boundary crossing
// iteration is computed analytically so the hot loop is branch-free and
// atomics-free -> the compiler can keep many global_load_dwordx4 in flight
// (R1 post-mortem: per-iteration flush branch serialized loads, 1.9 TB/s).
__global__ __launch_bounds__(256) void seg_mean_kernel(
    const float4* __restrict__ ff, const float4* __restrict__ fc,
    const int* __restrict__ len_f, const int* __restrict__ len_c,
    float* __restrict__ outbuf, int fineBlocks, int iterF, int iterC, int nRep)
{
    __shared__ int   s_cum[NSEG];
    __shared__ float s_inv[NSEG];
    const bool fine = (int)blockIdx.x < fineBlocks;
    const int* len = fine ? len_f : len_c;
    if (threadIdx.x == 0) {
        int c = 0;
        for (int i = 0; i < NSEG; ++i) {
            int l = len[i];
            c += l;
            s_cum[i] = c;
            s_inv[i] = 1.0f / (float)l;
        }
    }
    __syncthreads();

    const int t = threadIdx.x;
    float* rep = outbuf + ((int)blockIdx.x % nRep) * OUT_ELEMS;

    int base, iters, colMask, rowShift, outOff;
    const float4* src;
    if (fine) {
        base = (int)blockIdx.x * 256 * iterF;  // float4 index
        iters = iterF; colMask = 31; rowShift = 5; outOff = 256; src = ff;
    } else {
        base = ((int)blockIdx.x - fineBlocks) * 256 * iterC;
        iters = iterC; colMask = 63; rowShift = 6; outOff = 0; src = fc;
    }
    const int col = (t & colMask) << 2;  // float column within D
    const int idx0 = base + t;

    int seg = 0;
    {
        int row = idx0 >> rowShift;
        while (row >= s_cum[seg]) ++seg;
    }
    int curEnd = s_cum[seg];
    float4 acc = make_float4(0.f, 0.f, 0.f, 0.f);

    int i = 0;
    for (;;) {
        // first iteration at/after the segment boundary for this thread
        int iCross = ((curEnd << rowShift) - idx0 + 255) >> 8;
        int spanEnd = iCross < iters ? iCross : iters;
        #pragma unroll 8
        for (; i < spanEnd; ++i) {           // branch-free, atomics-free span
            const float4 v = src[idx0 + (i << 8)];
            acc.x += v.x; acc.y += v.y; acc.z += v.z; acc.w += v.w;
        }
        // flush current segment's partial (pre-scaled by 1/len)
        {
            const float inv = s_inv[seg];
            float* o = rep + seg * OUT_COLS + outOff + col;
            atomicAdd(o + 0, acc.x * inv);
            atomicAdd(o + 1, acc.y * inv);
            atomicAdd(o + 2, acc.z * inv);
            atomicAdd(o + 3, acc.w * inv);
        }
        if (i >= iters) break;
        acc = make_float4(0.f, 0.f, 0.f, 0.f);
        const int r = (idx0 + (i << 8)) >> rowShift;
        while (r >= s_cum[seg]) ++seg;
        curEnd = s_cum[seg];
    }
}

// Sum the nRep replicas into d_out (also provides the zero-init of d_out,
// which the harness re-poisons to 0xAA before every timed launch).
__global__ __launch_bounds__(256) void reduce_replicas_kernel(
    const float* __restrict__ ws, float* __restrict__ out, int nRep)
{
    const int j = blockIdx.x * blockDim.x + threadIdx.x;
    if (j < OUT_ELEMS) {
        float s = 0.f;
        for (int r = 0; r < nRep; ++r) s += ws[r * OUT_ELEMS + j];
        out[j] = s;
    }
}

extern "C" void kernel_launch(void* const* d_in, const int* in_sizes, int n_in,
                              void* d_out, int out_size, void* d_ws, size_t ws_size,
                              hipStream_t stream) {
    const float4* ff = (const float4*)d_in[0];   // feats_f [524288,128] f32
    const float4* fc = (const float4*)d_in[1];   // feats_c [32768,256]  f32
    const int* lf = (const int*)d_in[2];         // lengths_f [16] i32
    const int* lc = (const int*)d_in[3];         // lengths_c [16] i32
    float* out = (float*)d_out;                  // [16,384] f32

    const int NF4 = in_sizes[0] / 4;             // 16,777,216 float4
    const int NC4 = in_sizes[1] / 4;             //  2,097,152 float4
    const int iterF = 32, iterC = 16;
    const int fineBlocks   = NF4 / (256 * iterF);   // 2048
    const int coarseBlocks = NC4 / (256 * iterC);   // 512

    int nRep = (int)(ws_size / (OUT_ELEMS * sizeof(float)));
    if (nRep > 32) nRep = 32;
    if (nRep < 1)  nRep = 1;

    const size_t repBytes = (size_t)nRep * OUT_ELEMS * sizeof(float);
    hipMemsetAsync(d_ws, 0, repBytes, stream);

    seg_mean_kernel<<<fineBlocks + coarseBlocks, 256, 0, stream>>>(
        ff, fc, lf, lc, (float*)d_ws, fineBlocks, iterF, iterC, nRep);

    reduce_replicas_kernel<<<(OUT_ELEMS + 255) / 256, 256, 0, stream>>>(
        (const float*)d_ws, out, nRep);
}